// Round 3
// baseline (7039.949 us; speedup 1.0000x reference)
//
#include <hip/hip_runtime.h>
#include <hip/hip_fp16.h>
#include <hip/hip_cooperative_groups.h>

namespace cg = cooperative_groups;

#define NN 8192
#define NCOLS 101      // y + 100 probes
#define CPW 112        // Vp stored columns (101 used, 112 allocated)
#define BN 128         // compute columns (padded; Pb cols 101..127 are zero)
#define BM 128
#define KSPL 8
#define KCH (NN / KSPL)    // 1024 fp8 elems (=bytes) per split
#define NSTEP (KCH / 128)  // 8 steps of BK=128
#define PITER 30
#define PVLD 104           // pvp row stride (101 rounded up)
#define NSMALL 23424       // RS31 rsp8(in PV slot) AL30 BE30 PN31 SC31, x128 floats

typedef __attribute__((ext_vector_type(4))) float f32x4;

__device__ __forceinline__ void async_copy16(const void* g, void* l) {
  __builtin_amdgcn_global_load_lds(
      (const __attribute__((address_space(1))) unsigned int*)g,
      (__attribute__((address_space(3))) unsigned int*)l, 16, 0, 0);
}

__device__ __forceinline__ unsigned int pack_fp8x4(float x, float y, float z, float w) {
  unsigned int v = __builtin_amdgcn_cvt_pk_fp8_f32(x, y, 0, false);
  v = __builtin_amdgcn_cvt_pk_fp8_f32(z, w, v, true);
  return v;
}

// valid result on thread 0 only. Leading __syncthreads makes back-to-back calls safe.
__device__ __forceinline__ float block_sum(float v) {
  __shared__ float sw[4];
  __syncthreads();
  #pragma unroll
  for (int o = 32; o > 0; o >>= 1) v += __shfl_down(v, o);
  int w = threadIdx.x >> 6;
  if ((threadIdx.x & 63) == 0) sw[w] = v;
  __syncthreads();
  float r = 0.f;
  if (threadIdx.x < 4) r = sw[threadIdx.x];
  r += __shfl_down(r, 2);
  r += __shfl_down(r, 1);
  return r;
}

// ============================================================================
// Fused cooperative CG: init + 30 x (gemm -> sync -> update1 -> sync -> update2
// -> sync) in ONE dispatch. R2 post-mortem: 96 dispatches x ~12us launch gap
// dominated the 1989us total (kernels themselves model to ~15us/iter). grid.sync()
// provides device-scope release/acquire (L2 wb/inv) for cross-XCD Vp/pvp/rsp
// visibility. Grid 512x256 = exactly 2 blocks/CU (launch_bounds caps VGPR, LDS
// 64KB <= 80KB) so cooperative co-residency is structural.
// rs_new: per-row-chunk partials rsp[8][c] + redundant 8-way sum after sync
// (replaces atomicAdd — no atomics anywhere in the loop).
// ============================================================================
__global__ __launch_bounds__(256, 2) void cg_fused(
    const float* __restrict__ K, const float* __restrict__ y,
    const float* __restrict__ Z, unsigned char* __restrict__ Kb,
    unsigned char* __restrict__ Pb, float* __restrict__ P,
    float* __restrict__ R, __half* __restrict__ Vp, float* __restrict__ X0,
    float* __restrict__ pvp, float* __restrict__ SM) {
  cg::grid_group grid = cg::this_grid();
  // dbuf A (2x16KB) + dbuf B (2x16KB) = 64 KB; epilogue sC (128x113 f32 = 57.9 KB)
  // overlays the same memory after each K-loop's final barrier.
  __shared__ __align__(16) unsigned char smem[65536];
  unsigned char* sA = smem;          // [2][BM*128]
  unsigned char* sB = smem + 32768;  // [2][BN*128]
  float* sC = (float*)smem;          // [BM][113], post-K-loop overlay
  __shared__ float s_alpha;

  float* RS = SM;                // [31][128]
  float* rsp = SM + 3968;        // [8][128]  per-row-chunk |R|^2 partials
  float* AL = SM + 7808;         // [30][128]
  float* BE = SM + 11648;        // [30][128]
  float* PN = SM + 15488;        // [31][128]
  float* SC = SM + 19456;        // [31][128]

  int b = blockIdx.x;
  int t = threadIdx.x;
  int lane = t & 63;
  int w = t >> 6;

  // ---- INIT1: cast K->fp8; init P/R/Pb from y,Z; zero X0/SM/Pb-padding ----
  for (size_t i = ((size_t)b * 256 + t) * 4; i < (size_t)NN * NN; i += (size_t)512 * 1024) {
    float4 f = *(const float4*)(K + i);
    *(unsigned int*)(Kb + i) = pack_fp8x4(f.x, f.y, f.z, f.w);
  }
  for (int v = b; v < 3232; v += 512) {  // 32 x 101 virtual blocks
    int xi = v & 31, c = v >> 5;
    int i = xi * 256 + t;
    float val = (c == 0) ? y[i] : Z[(size_t)i * 100 + (c - 1)];
    size_t off = (size_t)c * NN + i;
    P[off] = val;
    R[off] = val;
    Pb[off] = (unsigned char)(__builtin_amdgcn_cvt_pk_fp8_f32(val, 0.f, 0, false) & 0xFF);
  }
  {
    const int total = 8192 + NSMALL + 27 * NN;
    for (int i = b * 256 + t; i < total; i += 512 * 256) {
      if (i < 8192) X0[i] = 0.f;
      else if (i < 8192 + NSMALL) SM[i - 8192] = 0.f;
      else Pb[(size_t)NCOLS * NN + (i - (8192 + NSMALL))] = 0;
    }
  }
  grid.sync();
  // ---- INIT2: rs0 = |y|^2 (block 0 only; runs after SM was zeroed) ----
  if (b == 0) {
    float s = 0.f;
    for (int i = t; i < NN; i += 256) { float vv = y[i]; s += vv * vv; }
    float tot = block_sum(s);
    if (t == 0) { RS[0] = tot; PN[0] = tot; }
    if (t >= 1 && t <= 100) { RS[t] = (float)NN; PN[t] = (float)NN; }
    if (t < 128) SC[t] = 1.f;
  }
  grid.sync();

  // ---- gemm-phase invariants ----
  int kz = b & 7;                // K-split: matches round-robin XCD mapping
  int rb = b >> 3;
  int r0 = rb * BM;
  int k0 = kz * KCH;
  int lrow = lane >> 3;          // 0..7
  int gseg = (lane & 7) ^ lrow;  // XOR-swizzled 16B slot within 128B row
  int mm = lane & 15;
  int quad = lane >> 4;
  int q1 = quad >> 1, q0 = quad & 1;
  int wm = w >> 1, wn = w & 1;   // wave grid 2M x 2N, wave tile 64x64
  int aBase[4], aXor[4], bBase[4], bXor[4];
  #pragma unroll
  for (int i = 0; i < 4; ++i) {
    int arow = wm * 64 + i * 16 + mm;
    aBase[i] = arow * 128 + (q0 << 3);
    aXor[i] = (arow & 7) << 4;
    int bcol = wn * 64 + i * 16 + mm;
    bBase[i] = bcol * 128 + (q0 << 3);
    bXor[i] = (bcol & 7) << 4;
  }
  const size_t SPL = (size_t)CPW * NN;
  // update-phase virtual blocks: v = c*8 + x over [0,808); this block owns
  // v1 = b and (if b < 296) v2 = 512 + b.
  int vx = b & 7;
  int vc1 = b >> 3;
  bool has2 = (b < 296);
  int vc2 = 64 + (b >> 3);

  for (int it = 0; it < PITER; ++it) {
    const float* SCit = SC + (size_t)it * 128;
    // ================= PHASE A: gemm (Vp[kz] = K-chunk @ Phat, pv partials) =========
    f32x4 acc[4][4];
    #pragma unroll
    for (int i = 0; i < 4; ++i)
      #pragma unroll
      for (int j = 0; j < 4; ++j) acc[i][j] = (f32x4){0.f, 0.f, 0.f, 0.f};

    auto stage = [&](int s, int buf) {
      int kk = k0 + s * 128;
      #pragma unroll
      for (int q = 0; q < 4; ++q) {  // wave w stages rows/cols w*32 + q*8 + lrow
        async_copy16(Kb + (size_t)(r0 + w * 32 + q * 8 + lrow) * NN + kk + gseg * 16,
                     sA + buf * 16384 + (w * 32 + q * 8) * 128);
        async_copy16(Pb + (size_t)(w * 32 + q * 8 + lrow) * NN + kk + gseg * 16,
                     sB + buf * 16384 + (w * 32 + q * 8) * 128);
      }
    };

    stage(0, 0);
    __syncthreads();  // vmcnt(0): prologue tile landed

    #pragma unroll 2
    for (int s = 0; s < NSTEP; ++s) {
      int cur = s & 1;
      if (s + 1 < NSTEP) stage(s + 1, cur ^ 1);  // prefetch next tile
      const unsigned char* A = sA + cur * 16384;
      const unsigned char* B = sB + cur * 16384;
      #pragma unroll
      for (int kh = 0; kh < 4; ++kh) {
        int s16 = (kh * 2 + q1) << 4;
        long long aF[4], bF[4];
        #pragma unroll
        for (int i = 0; i < 4; ++i) {
          aF[i] = *(const long long*)(A + aBase[i] + (s16 ^ aXor[i]));
          bF[i] = *(const long long*)(B + bBase[i] + (s16 ^ bXor[i]));
        }
        #pragma unroll
        for (int i = 0; i < 4; ++i)
          #pragma unroll
          for (int j = 0; j < 4; ++j)
            acc[i][j] = __builtin_amdgcn_mfma_f32_16x16x32_fp8_fp8(aF[i], bF[j], acc[i][j], 0, 0, 0);
      }
      __syncthreads();  // lgkmcnt(0) WAR + vmcnt(0) RAW for the dbuf swap
    }
    // epilogue: transpose through LDS (C/D frag layout: col=lane&15, row=quad*4+r)
    #pragma unroll
    for (int i = 0; i < 4; ++i)
      #pragma unroll
      for (int j = 0; j < 4; ++j) {
        int ctile = wn * 64 + j * 16;
        if (ctile >= CPW) continue;
        #pragma unroll
        for (int r = 0; r < 4; ++r)
          sC[(wm * 64 + i * 16 + quad * 4 + r) * 113 + ctile + mm] = acc[i][j][r];
      }
    __syncthreads();
    {
      __half* Vout = Vp + (size_t)kz * SPL;
      for (int idx = t; idx < BM * CPW; idx += 256) {
        int col = idx >> 7;
        int row = idx & 127;
        if (col < NCOLS)
          Vout[(size_t)col * NN + r0 + row] = __float2half(sC[row * 113 + col] * SCit[col]);
      }
      // pv partial: wave g handles cols {g, g+4, ...}
      int rr = t & 63;
      int g = t >> 6;
      for (int j = 0; j < 26; ++j) {
        int c = g + j * 4;
        float prod = 0.f;
        if (c < NCOLS)
          prod = (sC[rr * 113 + c] * P[(size_t)c * NN + r0 + rr] +
                  sC[(rr + 64) * 113 + c] * P[(size_t)c * NN + r0 + 64 + rr]) * SCit[c];
        #pragma unroll
        for (int o = 32; o > 0; o >>= 1) prod += __shfl_down(prod, o);
        if (rr == 0 && c < NCOLS) pvp[(size_t)b * PVLD + c] = prod;
      }
    }
    grid.sync();

    // ================= PHASE B: alpha; R -= a*V; X0; rsp partials =================
    for (int rep = 0; rep < 2; ++rep) {
      if (rep == 1 && !has2) break;
      int c = (rep == 0) ? vc1 : vc2;
      float pvv = pvp[(size_t)t * PVLD + c] + pvp[(size_t)(t + 256) * PVLD + c];
      float pvtot = block_sum(pvv);
      if (t == 0) s_alpha = RS[(size_t)it * 128 + c] / pvtot;
      __syncthreads();
      float alpha = s_alpha;
      size_t off = (size_t)c * NN + vx * 1024 + t * 4;
      float4 vsum = {0.f, 0.f, 0.f, 0.f};
      #pragma unroll
      for (int sp = 0; sp < KSPL; ++sp) {
        const __half2* ph = (const __half2*)(Vp + sp * SPL + off);
        float2 f01 = __half22float2(ph[0]);
        float2 f23 = __half22float2(ph[1]);
        vsum.x += f01.x; vsum.y += f01.y; vsum.z += f23.x; vsum.w += f23.y;
      }
      float4 r = *(float4*)(R + off);
      r.x -= alpha * vsum.x; r.y -= alpha * vsum.y;
      r.z -= alpha * vsum.z; r.w -= alpha * vsum.w;
      *(float4*)(R + off) = r;
      if (c == 0) {
        size_t xo = (size_t)vx * 1024 + t * 4;
        float4 x = *(float4*)(X0 + xo);
        float4 p = *(const float4*)(P + off);
        x.x += alpha * p.x; x.y += alpha * p.y;
        x.z += alpha * p.z; x.w += alpha * p.w;
        *(float4*)(X0 + xo) = x;
      }
      float rn = r.x * r.x + r.y * r.y + r.z * r.z + r.w * r.w;
      float tot = block_sum(rn);
      if (t == 0) {
        rsp[vx * 128 + c] = tot;
        if (vx == 0) AL[(size_t)it * 128 + c] = alpha;
      }
    }
    grid.sync();

    // ================= PHASE C: beta; P = R + b*P; Pb = fp8(P/sc) =================
    for (int rep = 0; rep < 2; ++rep) {
      if (rep == 1 && !has2) break;
      int c = (rep == 0) ? vc1 : vc2;
      float rsn = 0.f;
      #pragma unroll
      for (int xx = 0; xx < 8; ++xx) rsn += rsp[xx * 128 + c];
      float beta = rsn / RS[(size_t)it * 128 + c];
      if (it < PITER - 1) {  // last iter: P/Pb dead (only BE[29] still needed)
        float pnn = rsn + beta * beta * PN[(size_t)it * 128 + c];
        float sc = exp2f(roundf(0.5f * log2f(pnn * (1.f / 8192.f))));
        float inv = 1.f / sc;
        size_t off = (size_t)c * NN + vx * 1024 + t * 4;
        float4 r = *(const float4*)(R + off);
        float4 p = *(float4*)(P + off);
        p.x = r.x + beta * p.x; p.y = r.y + beta * p.y;
        p.z = r.z + beta * p.z; p.w = r.w + beta * p.w;
        *(float4*)(P + off) = p;
        *(unsigned int*)(Pb + off) = pack_fp8x4(p.x * inv, p.y * inv, p.z * inv, p.w * inv);
        if (vx == 0 && t == 0) {
          PN[(size_t)(it + 1) * 128 + c] = pnn;
          SC[(size_t)(it + 1) * 128 + c] = sc;
          RS[(size_t)(it + 1) * 128 + c] = rsn;
        }
      }
      if (vx == 0 && t == 0) BE[(size_t)it * 128 + c] = beta;
    }
    grid.sync();
  }
}

// ============================================================================
// Fallback path (used only if cooperative launch is refused): R2 kernels.
// ============================================================================
__global__ __launch_bounds__(256, 2) void gemm_kernel(
    const unsigned char* __restrict__ Kb,
    const unsigned char* __restrict__ Pb,
    const float* __restrict__ Pf,
    const float* __restrict__ SCit,
    __half* __restrict__ Vp,
    float* __restrict__ pvp) {
  __shared__ __align__(16) unsigned char smem[65536];
  unsigned char* sA = smem;
  unsigned char* sB = smem + 32768;
  float* sC = (float*)smem;

  int bx = blockIdx.x;
  int kz = bx & 7;
  int rb = bx >> 3;
  int tid = threadIdx.x;
  int lane = tid & 63;
  int w = tid >> 6;
  int r0 = rb * BM;
  int k0 = kz * KCH;
  int lrow = lane >> 3;
  int gseg = (lane & 7) ^ lrow;
  int mm = lane & 15;
  int quad = lane >> 4;
  int q1 = quad >> 1, q0 = quad & 1;
  int wm = w >> 1, wn = w & 1;

  int aBase[4], aXor[4], bBase[4], bXor[4];
  #pragma unroll
  for (int i = 0; i < 4; ++i) {
    int arow = wm * 64 + i * 16 + mm;
    aBase[i] = arow * 128 + (q0 << 3);
    aXor[i] = (arow & 7) << 4;
    int bcol = wn * 64 + i * 16 + mm;
    bBase[i] = bcol * 128 + (q0 << 3);
    bXor[i] = (bcol & 7) << 4;
  }

  f32x4 acc[4][4];
  #pragma unroll
  for (int i = 0; i < 4; ++i)
    #pragma unroll
    for (int j = 0; j < 4; ++j) acc[i][j] = (f32x4){0.f, 0.f, 0.f, 0.f};

  auto stage = [&](int s, int buf) {
    int kk = k0 + s * 128;
    #pragma unroll
    for (int q = 0; q < 4; ++q) {
      async_copy16(Kb + (size_t)(r0 + w * 32 + q * 8 + lrow) * NN + kk + gseg * 16,
                   sA + buf * 16384 + (w * 32 + q * 8) * 128);
      async_copy16(Pb + (size_t)(w * 32 + q * 8 + lrow) * NN + kk + gseg * 16,
                   sB + buf * 16384 + (w * 32 + q * 8) * 128);
    }
  };

  stage(0, 0);
  __syncthreads();

  #pragma unroll 2
  for (int s = 0; s < NSTEP; ++s) {
    int cur = s & 1;
    if (s + 1 < NSTEP) stage(s + 1, cur ^ 1);
    const unsigned char* A = sA + cur * 16384;
    const unsigned char* B = sB + cur * 16384;
    #pragma unroll
    for (int kh = 0; kh < 4; ++kh) {
      int s16 = (kh * 2 + q1) << 4;
      long long aF[4], bF[4];
      #pragma unroll
      for (int i = 0; i < 4; ++i) {
        aF[i] = *(const long long*)(A + aBase[i] + (s16 ^ aXor[i]));
        bF[i] = *(const long long*)(B + bBase[i] + (s16 ^ bXor[i]));
      }
      #pragma unroll
      for (int i = 0; i < 4; ++i)
        #pragma unroll
        for (int j = 0; j < 4; ++j)
          acc[i][j] = __builtin_amdgcn_mfma_f32_16x16x32_fp8_fp8(aF[i], bF[j], acc[i][j], 0, 0, 0);
    }
    __syncthreads();
  }
  #pragma unroll
  for (int i = 0; i < 4; ++i)
    #pragma unroll
    for (int j = 0; j < 4; ++j) {
      int ctile = wn * 64 + j * 16;
      if (ctile >= CPW) continue;
      #pragma unroll
      for (int r = 0; r < 4; ++r)
        sC[(wm * 64 + i * 16 + quad * 4 + r) * 113 + ctile + mm] = acc[i][j][r];
    }
  __syncthreads();
  const size_t SPL = (size_t)CPW * NN;
  __half* Vout = Vp + (size_t)kz * SPL;
  for (int idx = tid; idx < BM * CPW; idx += 256) {
    int col = idx >> 7;
    int row = idx & 127;
    if (col < NCOLS)
      Vout[(size_t)col * NN + r0 + row] = __float2half(sC[row * 113 + col] * SCit[col]);
  }
  int rr = tid & 63;
  int g = tid >> 6;
  for (int j = 0; j < 26; ++j) {
    int c = g + j * 4;
    float prod = 0.f;
    if (c < NCOLS)
      prod = (sC[rr * 113 + c] * Pf[(size_t)c * NN + r0 + rr] +
              sC[(rr + 64) * 113 + c] * Pf[(size_t)c * NN + r0 + 64 + rr]) * SCit[c];
    #pragma unroll
    for (int o = 32; o > 0; o >>= 1) prod += __shfl_down(prod, o);
    if (rr == 0 && c < NCOLS) pvp[(size_t)bx * PVLD + c] = prod;
  }
}

__global__ void update1_kernel(const __half* __restrict__ Vp,
                               const float* __restrict__ Pf,
                               float* __restrict__ R,
                               float* __restrict__ X0,
                               const float* __restrict__ pvp,
                               const float* __restrict__ rs,
                               float* __restrict__ rs_new,
                               float* __restrict__ alphas) {
  const size_t SPL = (size_t)CPW * NN;
  __shared__ float s_alpha;
  int c = blockIdx.y;
  int t = threadIdx.x;
  float pvv = pvp[(size_t)t * PVLD + c] + pvp[(size_t)(t + 256) * PVLD + c];
  float pvtot = block_sum(pvv);
  if (t == 0) s_alpha = rs[c] / pvtot;
  __syncthreads();
  float alpha = s_alpha;

  size_t off = (size_t)c * NN + blockIdx.x * 1024 + t * 4;
  float4 v = {0.f, 0.f, 0.f, 0.f};
  #pragma unroll
  for (int sp = 0; sp < KSPL; ++sp) {
    const __half2* p = (const __half2*)(Vp + sp * SPL + off);
    float2 f01 = __half22float2(p[0]);
    float2 f23 = __half22float2(p[1]);
    v.x += f01.x; v.y += f01.y; v.z += f23.x; v.w += f23.y;
  }
  float4 r = *(float4*)(R + off);
  r.x -= alpha * v.x; r.y -= alpha * v.y; r.z -= alpha * v.z; r.w -= alpha * v.w;
  *(float4*)(R + off) = r;
  if (c == 0) {
    size_t xo = blockIdx.x * 1024 + t * 4;
    float4 x = *(float4*)(X0 + xo);
    float4 p = *(const float4*)(Pf + off);
    x.x += alpha * p.x; x.y += alpha * p.y; x.z += alpha * p.z; x.w += alpha * p.w;
    *(float4*)(X0 + xo) = x;
  }
  float rn = r.x * r.x + r.y * r.y + r.z * r.z + r.w * r.w;
  float tot = block_sum(rn);
  if (t == 0) {
    atomicAdd(rs_new + c, tot);
    if (blockIdx.x == 0) alphas[c] = alpha;
  }
}

__global__ void update2_kernel(const float* __restrict__ R,
                               float* __restrict__ P,
                               unsigned char* __restrict__ Pb,
                               const float* __restrict__ rs,
                               const float* __restrict__ rs_new,
                               const float* __restrict__ PNold,
                               float* __restrict__ PNnew,
                               float* __restrict__ SCnew,
                               float* __restrict__ betas) {
  int c = blockIdx.y;
  float rsn = rs_new[c];
  float beta = rsn / rs[c];
  float pnn = rsn + beta * beta * PNold[c];
  float sc = exp2f(roundf(0.5f * log2f(pnn * (1.f / 8192.f))));
  float inv = 1.f / sc;
  size_t off = (size_t)c * NN + blockIdx.x * 1024 + threadIdx.x * 4;
  float4 r = *(const float4*)(R + off);
  float4 p = *(float4*)(P + off);
  p.x = r.x + beta * p.x; p.y = r.y + beta * p.y;
  p.z = r.z + beta * p.z; p.w = r.w + beta * p.w;
  *(float4*)(P + off) = p;
  *(unsigned int*)(Pb + off) = pack_fp8x4(p.x * inv, p.y * inv, p.z * inv, p.w * inv);
  if (threadIdx.x == 0 && blockIdx.x == 0) {
    betas[c] = beta;
    PNnew[c] = pnn;
    SCnew[c] = sc;
  }
}

__global__ void cast_k_kernel(const float* __restrict__ K, unsigned char* __restrict__ Kb) {
  size_t i = ((size_t)blockIdx.x * 256 + threadIdx.x) * 4;
  size_t stride = (size_t)gridDim.x * 1024;
  for (; i < (size_t)NN * NN; i += stride) {
    float4 f = *(const float4*)(K + i);
    *(unsigned int*)(Kb + i) = pack_fp8x4(f.x, f.y, f.z, f.w);
  }
}

__global__ void init_vec_kernel(const float* __restrict__ y, const float* __restrict__ Z,
                                float* __restrict__ P, float* __restrict__ R,
                                unsigned char* __restrict__ Pb) {
  int c = blockIdx.y;
  int i = blockIdx.x * 256 + threadIdx.x;
  float val = (c == 0) ? y[i] : Z[(size_t)i * 100 + (c - 1)];
  size_t off = (size_t)c * NN + i;
  P[off] = val;
  R[off] = val;
  Pb[off] = (unsigned char)(__builtin_amdgcn_cvt_pk_fp8_f32(val, 0.f, 0, false) & 0xFF);
}

__global__ void init_misc_kernel(float* __restrict__ X0, float* __restrict__ smalls,
                                 unsigned char* __restrict__ Pbpad) {
  const int total = 8192 + NSMALL + 27 * NN;
  for (int t = blockIdx.x * 256 + threadIdx.x; t < total; t += gridDim.x * 256) {
    if (t < 8192) X0[t] = 0.f;
    else if (t < 8192 + NSMALL) smalls[t - 8192] = 0.f;
    else Pbpad[t - (8192 + NSMALL)] = 0;
  }
}

__global__ void init_rs_kernel(const float* __restrict__ y, float* __restrict__ rs0,
                               float* __restrict__ pn0, float* __restrict__ sc0) {
  int t = threadIdx.x;
  float s = 0.f;
  for (int i = t; i < NN; i += 256) { float v = y[i]; s += v * v; }
  float tot = block_sum(s);
  if (t == 0) { rs0[0] = tot; pn0[0] = tot; }
  if (t >= 1 && t <= 100) { rs0[t] = (float)NN; pn0[t] = (float)NN; }
  if (t < 128) sc0[t] = 1.f;
}

// ---------------- SLQ: Sturm bisection + Gauss-weight recurrence, fp64 ----------------
// Kept OUT of the cooperative kernel: d[30]+e[30] fp64 arrays (~120 VGPR) would
// threaten the 2-blocks/CU co-residency the grid.sync depends on.
__global__ __launch_bounds__(64, 1) void slq_kernel(
    const float* __restrict__ AL, const float* __restrict__ BE,
    float* __restrict__ QP) {
  __shared__ double sd[PITER], se[PITER];
  int lane = threadIdx.x;
  int c = blockIdx.x + 1;
  if (lane < PITER) {
    double a = (double)AL[lane * 128 + c];
    double dd = 1.0 / a;
    if (lane > 0) {
      double ap = (double)AL[(lane - 1) * 128 + c];
      double bp = (double)BE[(lane - 1) * 128 + c];
      dd += bp / ap;
    }
    sd[lane] = dd;
    double ee = 0.0;
    if (lane < PITER - 1) {
      double bq = (double)BE[lane * 128 + c];
      ee = sqrt(bq) / a;
    }
    se[lane] = ee;
  }
  __syncthreads();
  double d[PITER], e[PITER];
  #pragma unroll
  for (int i = 0; i < PITER; ++i) { d[i] = sd[i]; e[i] = se[i]; }

  float quadk = 0.f;
  if (lane < PITER) {
    double lo = 1e300, hi = -1e300;
    #pragma unroll
    for (int i = 0; i < PITER; ++i) {
      double r = e[i] + (i > 0 ? e[i - 1] : 0.0);
      lo = fmin(lo, d[i] - r);
      hi = fmax(hi, d[i] + r);
    }
    int k = lane;
    for (int it = 0; it < 48; ++it) {
      double mid = 0.5 * (lo + hi);
      int cnt = 0;
      double q = d[0] - mid;
      cnt += (q < 0.0);
      #pragma unroll
      for (int i = 1; i < PITER; ++i) {
        double aq = fabs(q);
        if (aq < 1e-30) q = (q < 0.0) ? -1e-30 : 1e-30;
        q = d[i] - mid - (e[i - 1] * e[i - 1]) / q;
        cnt += (q < 0.0);
      }
      if (cnt > k) hi = mid; else lo = mid;
    }
    double lam = 0.5 * (lo + hi);
    double e0 = fmax(e[0], 1e-150);
    double vprev = 1.0;
    double vcur = (lam - d[0]) / e0;
    double s = 1.0 + vcur * vcur;
    double scale2 = 1.0;
    #pragma unroll
    for (int i = 1; i < PITER - 1; ++i) {
      double ei = fmax(e[i], 1e-150);
      double vnext = ((lam - d[i]) * vcur - e[i - 1] * vprev) / ei;
      if (fabs(vnext) > 1e150) {
        vnext *= 1e-150; vcur *= 1e-150; s *= 1e-300; scale2 *= 1e-300;
      }
      vprev = vcur; vcur = vnext;
      s += vcur * vcur;
    }
    double w = scale2 / s;
    double lc = lam > 1e-12 ? lam : 1e-12;
    quadk = (float)(w * log(lc));
  }
  #pragma unroll
  for (int o = 32; o > 0; o >>= 1) quadk += __shfl_down(quadk, o);
  if (lane == 0) QP[blockIdx.x] = quadk;
}

__global__ void final2_kernel(const float* __restrict__ y, const float* __restrict__ X0,
                              const float* __restrict__ QP, float* __restrict__ out) {
  int t = threadIdx.x;
  float s = 0.f;
  for (int i = t; i < NN; i += 256) s += y[i] * X0[i];
  float ydot = block_sum(s);
  __syncthreads();
  float q = (t < 100) ? QP[t] : 0.f;
  float qsum = block_sum(q);
  if (t == 0) {
    float logdet = (float)NN * (qsum * 0.01f);
    out[0] = -0.5f * ydot - 0.5f * logdet - (float)NN * 0.5f * 1.8378770664093454f;
  }
}

extern "C" void kernel_launch(void* const* d_in, const int* in_sizes, int n_in,
                              void* d_out, int out_size, void* d_ws, size_t ws_size,
                              hipStream_t stream) {
  const float* K = (const float*)d_in[0];
  const float* y = (const float*)d_in[1];
  const float* Z = (const float*)d_in[2];
  float* out = (float*)d_out;
  char* ws = (char*)d_ws;
  if (ws_size < 89796096ull) return;  // need ~85.6 MiB

  unsigned char* Kb = (unsigned char*)(ws + 0ull);        // 67,108,864
  unsigned char* Pb = (unsigned char*)(ws + 67108864ull); //  1,048,576 (128 cols)
  float* P   = (float*)(ws + 68157440ull);                //  3,309,568 (101 cols)
  float* R   = (float*)(ws + 71467008ull);                //  3,309,568
  __half* Vp = (__half*)(ws + 74776576ull);               // 14,680,064 (8 splits x 112 cols, fp16)
  float* X0  = (float*)(ws + 89456640ull);                //     32,768
  float* PVP = (float*)(ws + 89489408ull);                //    212,992 (512 x 104)
  float* SM  = (float*)(ws + 89702400ull);                //     93,696 scalar block
  float* RS = SM;               // [31][128]
  float* AL = SM + 7808;        // [30][128]
  float* BE = SM + 11648;       // [30][128]
  float* PN = SM + 15488;       // [31][128]
  float* SC = SM + 19456;       // [31][128]
  float* QP = (float*)(ws + 74776576ull);  // 100 floats, reuses Vp after CG loop

  void* args[] = {(void*)&K, (void*)&y, (void*)&Z, (void*)&Kb, (void*)&Pb,
                  (void*)&P, (void*)&R, (void*)&Vp, (void*)&X0, (void*)&PVP,
                  (void*)&SM};
  hipError_t err = hipLaunchCooperativeKernel((const void*)cg_fused, dim3(512),
                                              dim3(256), args, 0, stream);
  if (err != hipSuccess) {
    // Fallback: multi-kernel path (96 dispatches), functionally identical.
    cast_k_kernel<<<8192, 256, 0, stream>>>(K, Kb);
    init_vec_kernel<<<dim3(32, 101), 256, 0, stream>>>(y, Z, P, R, Pb);
    init_misc_kernel<<<240, 256, 0, stream>>>(X0, SM, Pb + (size_t)NCOLS * NN);
    init_rs_kernel<<<1, 256, 0, stream>>>(y, RS, PN, SC);
    for (int it = 0; it < PITER; ++it) {
      gemm_kernel<<<512, 256, 0, stream>>>(Kb, Pb, P, SC + it * 128, Vp, PVP);
      update1_kernel<<<dim3(8, 101), 256, 0, stream>>>(Vp, P, R, X0, PVP,
          RS + it * 128, RS + (it + 1) * 128, AL + it * 128);
      update2_kernel<<<dim3(8, 101), 256, 0, stream>>>(R, P, Pb, RS + it * 128,
          RS + (it + 1) * 128, PN + it * 128, PN + (it + 1) * 128,
          SC + (it + 1) * 128, BE + it * 128);
    }
  }
  slq_kernel<<<100, 64, 0, stream>>>(AL, BE, QP);
  final2_kernel<<<1, 256, 0, stream>>>(y, X0, QP, out);
}

// Round 4
// 2032.038 us; speedup vs baseline: 3.4645x; 3.4645x over previous
//
#include <hip/hip_runtime.h>
#include <hip/hip_fp16.h>

#define NN 8192
#define NCOLS 101      // y + 100 probes
#define CPW 112        // Vp stored columns (101 used, 112 allocated)
#define BN 128         // compute columns (padded; Pb cols 101..127 are zero)
#define BM 128
#define KSPL 8
#define KCH (NN / KSPL)    // 1024 fp8 elems (=bytes) per split
#define NSTEP (KCH / 128)  // 8 steps of BK=128
#define PITER 30
#define PVLD 104           // pvp row stride (101 rounded up)
#define NSMALL 23424       // RS31 rsp8 AL30 BE30 PN31 SC31, x128 floats

typedef __attribute__((ext_vector_type(4))) float f32x4;

__device__ __forceinline__ void async_copy16(const void* g, void* l) {
  __builtin_amdgcn_global_load_lds(
      (const __attribute__((address_space(1))) unsigned int*)g,
      (__attribute__((address_space(3))) unsigned int*)l, 16, 0, 0);
}

__device__ __forceinline__ unsigned int pack_fp8x4(float x, float y, float z, float w) {
  unsigned int v = __builtin_amdgcn_cvt_pk_fp8_f32(x, y, 0, false);
  v = __builtin_amdgcn_cvt_pk_fp8_f32(z, w, v, true);
  return v;
}

// valid result on thread 0 only; leading barrier makes back-to-back calls safe
__device__ __forceinline__ float block_sum(float v) {
  __shared__ float sw[4];
  __syncthreads();
  #pragma unroll
  for (int o = 32; o > 0; o >>= 1) v += __shfl_down(v, o);
  int w = threadIdx.x >> 6;
  if ((threadIdx.x & 63) == 0) sw[w] = v;
  __syncthreads();
  float r = 0.f;
  if (threadIdx.x < 4) r = sw[threadIdx.x];
  r += __shfl_down(r, 2);
  r += __shfl_down(r, 1);
  return r;
}

// ---------------- GEMM: Vp[kz] = K-panel @ Phat (fp8 MFMA) + pv partials ----------------
// R3 post-mortem: gemm is DRAM-page-bound on Kb. Row-major Kb gave 128-B picks from
// 8-KB-strided rows (zero row-buffer locality, ~2 TB/s). Kb is now TILED at cast time:
// Kbt[panel=bx][step][row 0..127][128 B] — each block streams one contiguous 128-KB
// panel; each wave's global_load_lds covers 1 KB contiguous (the 6.3 TB/s m13 pattern).
// XOR swizzle (seg g holds logical seg g^(row&7)) permutes only WITHIN each 128-B line,
// so coalescing is unaffected and the LDS/ds_read side is unchanged.
// 128x128 block tile, 64x64 wave tile, 2-phase dbuf pipeline, one barrier per step.
__global__ __launch_bounds__(256, 2) void gemm_kernel(
    const unsigned char* __restrict__ Kbt,
    const unsigned char* __restrict__ Pb,
    const float* __restrict__ Pf,
    const float* __restrict__ SCit,
    __half* __restrict__ Vp,
    float* __restrict__ pvp) {
  // dbuf A (2x16KB) + dbuf B (2x16KB) = 64 KB; epilogue sC (128x113 f32 = 57.9 KB)
  // overlays the same memory after the K-loop's final barrier.
  __shared__ __align__(16) unsigned char smem[65536];
  unsigned char* sA = smem;          // [2][BM*128]
  unsigned char* sB = smem + 32768;  // [2][BN*128]
  float* sC = (float*)smem;          // [BM][113], post-loop overlay

  int bx = blockIdx.x;
  int kz = bx & 7;
  int rb = bx >> 3;
  int tid = threadIdx.x;
  int lane = tid & 63;
  int w = tid >> 6;
  int r0 = rb * BM;
  int k0 = kz * KCH;             // byte offset into P col (B operand, row-major)
  int lrow = lane >> 3;          // 0..7
  int gseg = (lane & 7) ^ lrow;  // swizzled 16B slot within 128B row
  int asrc = lrow * 128 + gseg * 16;  // per-lane offset within a tiled A row-group
  int mm = lane & 15;
  int quad = lane >> 4;
  int q1 = quad >> 1, q0 = quad & 1;
  int wm = w >> 1, wn = w & 1;   // wave grid 2M x 2N, wave tile 64x64

  const unsigned char* Apanel = Kbt + ((size_t)bx << 17);  // 128 KB contiguous

  int aBase[4], aXor[4], bBase[4], bXor[4];
  #pragma unroll
  for (int i = 0; i < 4; ++i) {
    int arow = wm * 64 + i * 16 + mm;
    aBase[i] = arow * 128 + (q0 << 3);
    aXor[i] = (arow & 7) << 4;
    int bcol = wn * 64 + i * 16 + mm;
    bBase[i] = bcol * 128 + (q0 << 3);
    bXor[i] = (bcol & 7) << 4;
  }

  f32x4 acc[4][4];
  #pragma unroll
  for (int i = 0; i < 4; ++i)
    #pragma unroll
    for (int j = 0; j < 4; ++j) acc[i][j] = (f32x4){0.f, 0.f, 0.f, 0.f};

  auto stage = [&](int s, int buf) {
    int kk = k0 + s * 128;
    #pragma unroll
    for (int q = 0; q < 4; ++q) {  // wave w stages rows/cols w*32 + q*8 + lrow
      async_copy16(Apanel + (s << 14) + (w * 32 + q * 8) * 128 + asrc,
                   sA + buf * 16384 + (w * 32 + q * 8) * 128);
      async_copy16(Pb + (size_t)(w * 32 + q * 8 + lrow) * NN + kk + gseg * 16,
                   sB + buf * 16384 + (w * 32 + q * 8) * 128);
    }
  };

  stage(0, 0);
  __syncthreads();  // vmcnt(0): prologue tile landed

  #pragma unroll 2
  for (int s = 0; s < NSTEP; ++s) {
    int cur = s & 1;
    if (s + 1 < NSTEP) stage(s + 1, cur ^ 1);  // prefetch next tile
    const unsigned char* A = sA + cur * 16384;
    const unsigned char* B = sB + cur * 16384;
    #pragma unroll
    for (int kh = 0; kh < 4; ++kh) {
      int s16 = (kh * 2 + q1) << 4;
      long long aF[4], bF[4];
      #pragma unroll
      for (int i = 0; i < 4; ++i) {
        aF[i] = *(const long long*)(A + aBase[i] + (s16 ^ aXor[i]));
        bF[i] = *(const long long*)(B + bBase[i] + (s16 ^ bXor[i]));
      }
      #pragma unroll
      for (int i = 0; i < 4; ++i)
        #pragma unroll
        for (int j = 0; j < 4; ++j)
          acc[i][j] = __builtin_amdgcn_mfma_f32_16x16x32_fp8_fp8(aF[i], bF[j], acc[i][j], 0, 0, 0);
    }
    __syncthreads();  // lgkmcnt(0) WAR + vmcnt(0) RAW for the dbuf swap
  }
  // epilogue: transpose through LDS (C/D frag layout: col=lane&15, row=quad*4+r)
  #pragma unroll
  for (int i = 0; i < 4; ++i)
    #pragma unroll
    for (int j = 0; j < 4; ++j) {
      int ctile = wn * 64 + j * 16;
      if (ctile >= CPW) continue;
      #pragma unroll
      for (int r = 0; r < 4; ++r)
        sC[(wm * 64 + i * 16 + quad * 4 + r) * 113 + ctile + mm] = acc[i][j][r];
    }
  __syncthreads();
  const size_t SPL = (size_t)CPW * NN;
  __half* Vout = Vp + (size_t)kz * SPL;
  for (int idx = tid; idx < BM * CPW; idx += 256) {
    int col = idx >> 7;
    int row = idx & 127;
    if (col < NCOLS)
      Vout[(size_t)col * NN + r0 + row] = __float2half(sC[row * 113 + col] * SCit[col]);
  }
  // pv partial: wave g handles cols {g, g+4, ...}; lanes = rows (coalesced P reads)
  int rr = tid & 63;
  int g = tid >> 6;
  for (int j = 0; j < 26; ++j) {
    int c = g + j * 4;
    float prod = 0.f;
    if (c < NCOLS)
      prod = (sC[rr * 113 + c] * Pf[(size_t)c * NN + r0 + rr] +
              sC[(rr + 64) * 113 + c] * Pf[(size_t)c * NN + r0 + 64 + rr]) * SCit[c];
    #pragma unroll
    for (int o = 32; o > 0; o >>= 1) prod += __shfl_down(prod, o);
    if (rr == 0 && c < NCOLS) pvp[(size_t)bx * PVLD + c] = prod;
  }
}

// ---------------- alpha; V=sum(Vp fp16); R -= a*V; X0 += a*P(:,0); rs_new = |R|^2 ----------------
__global__ void update1_kernel(const __half* __restrict__ Vp,
                               const float* __restrict__ Pf,
                               float* __restrict__ R,
                               float* __restrict__ X0,
                               const float* __restrict__ pvp,
                               const float* __restrict__ rs,
                               float* __restrict__ rs_new,
                               float* __restrict__ alphas) {
  const size_t SPL = (size_t)CPW * NN;
  __shared__ float s_alpha;
  int c = blockIdx.y;
  int t = threadIdx.x;
  // redundant per-block sum of the 512 pv partials (L2-resident, ~free)
  float pvv = pvp[(size_t)t * PVLD + c] + pvp[(size_t)(t + 256) * PVLD + c];
  float pvtot = block_sum(pvv);
  if (t == 0) s_alpha = rs[c] / pvtot;
  __syncthreads();
  float alpha = s_alpha;

  size_t off = (size_t)c * NN + blockIdx.x * 1024 + t * 4;
  float4 v = {0.f, 0.f, 0.f, 0.f};
  #pragma unroll
  for (int sp = 0; sp < KSPL; ++sp) {
    const __half2* p = (const __half2*)(Vp + sp * SPL + off);
    float2 f01 = __half22float2(p[0]);
    float2 f23 = __half22float2(p[1]);
    v.x += f01.x; v.y += f01.y; v.z += f23.x; v.w += f23.y;
  }
  float4 r = *(float4*)(R + off);
  r.x -= alpha * v.x; r.y -= alpha * v.y; r.z -= alpha * v.z; r.w -= alpha * v.w;
  *(float4*)(R + off) = r;
  if (c == 0) {
    size_t xo = blockIdx.x * 1024 + t * 4;
    float4 x = *(float4*)(X0 + xo);
    float4 p = *(const float4*)(Pf + off);
    x.x += alpha * p.x; x.y += alpha * p.y; x.z += alpha * p.z; x.w += alpha * p.w;
    *(float4*)(X0 + xo) = x;
  }
  float rn = r.x * r.x + r.y * r.y + r.z * r.z + r.w * r.w;
  float tot = block_sum(rn);
  if (t == 0) {
    atomicAdd(rs_new + c, tot);
    if (blockIdx.x == 0) alphas[c] = alpha;
  }
}

// ---------------- beta; P = R + b*P; Phat = fp8(P/scale); scale bookkeeping ----------------
__global__ void update2_kernel(const float* __restrict__ R,
                               float* __restrict__ P,
                               unsigned char* __restrict__ Pb,
                               const float* __restrict__ rs,
                               const float* __restrict__ rs_new,
                               const float* __restrict__ PNold,
                               float* __restrict__ PNnew,
                               float* __restrict__ SCnew,
                               float* __restrict__ betas) {
  int c = blockIdx.y;
  float rsn = rs_new[c];
  float beta = rsn / rs[c];
  float pnn = rsn + beta * beta * PNold[c];           // ||P_new||^2 (CG identity)
  float sc = exp2f(roundf(0.5f * log2f(pnn * (1.f / 8192.f))));
  float inv = 1.f / sc;
  size_t off = (size_t)c * NN + blockIdx.x * 1024 + threadIdx.x * 4;
  float4 r = *(const float4*)(R + off);
  float4 p = *(float4*)(P + off);
  p.x = r.x + beta * p.x; p.y = r.y + beta * p.y;
  p.z = r.z + beta * p.z; p.w = r.w + beta * p.w;
  *(float4*)(P + off) = p;
  *(unsigned int*)(Pb + off) = pack_fp8x4(p.x * inv, p.y * inv, p.z * inv, p.w * inv);
  if (threadIdx.x == 0 && blockIdx.x == 0) {
    betas[c] = beta;
    PNnew[c] = pnn;
    SCnew[c] = sc;
  }
}

// ---------------- init: cast K (f32 row-major) -> Kbt (fp8, per-block tiled panels) ----------
// Kbt layout: panel p = rb*8+kz (== gemm blockIdx), within panel: [step s][row 0..127][128 B],
// logical seg order (gemm's stage applies the XOR swizzle via its per-lane source offset).
// Element (r,c) of K -> p = (r>>7)*8 + (c>>10); s = (c>>7)&7; row = r&127; byte = c&127.
__global__ void cast_k_kernel(const float* __restrict__ K, unsigned char* __restrict__ Kbt) {
  for (size_t u = (size_t)blockIdx.x * 256 + threadIdx.x; u < (size_t)NN * NN / 16;
       u += (size_t)gridDim.x * 256) {
    size_t d = u * 16;
    int p = (int)(d >> 17);
    int rem = (int)(d & 131071);
    int s = rem >> 14;
    int row = (rem >> 7) & 127;
    int cb = rem & 127;
    int r = (p >> 3) * 128 + row;
    int c = (p & 7) * KCH + s * 128 + cb;
    const float* src = K + (size_t)r * NN + c;
    float4 f0 = *(const float4*)(src);
    float4 f1 = *(const float4*)(src + 4);
    float4 f2 = *(const float4*)(src + 8);
    float4 f3 = *(const float4*)(src + 12);
    uint4 o;
    o.x = pack_fp8x4(f0.x, f0.y, f0.z, f0.w);
    o.y = pack_fp8x4(f1.x, f1.y, f1.z, f1.w);
    o.z = pack_fp8x4(f2.x, f2.y, f2.z, f2.w);
    o.w = pack_fp8x4(f3.x, f3.y, f3.z, f3.w);
    *(uint4*)(Kbt + d) = o;
  }
}

__global__ void init_vec_kernel(const float* __restrict__ y, const float* __restrict__ Z,
                                float* __restrict__ P, float* __restrict__ R,
                                unsigned char* __restrict__ Pb) {
  int c = blockIdx.y;
  int i = blockIdx.x * 256 + threadIdx.x;
  float val = (c == 0) ? y[i] : Z[(size_t)i * 100 + (c - 1)];
  size_t off = (size_t)c * NN + i;
  P[off] = val;
  R[off] = val;
  Pb[off] = (unsigned char)(__builtin_amdgcn_cvt_pk_fp8_f32(val, 0.f, 0, false) & 0xFF);
}

__global__ void init_misc_kernel(float* __restrict__ X0, float* __restrict__ smalls,
                                 unsigned char* __restrict__ Pbpad) {
  const int total = 8192 + NSMALL + 27 * NN;
  for (int t = blockIdx.x * 256 + threadIdx.x; t < total; t += gridDim.x * 256) {
    if (t < 8192) X0[t] = 0.f;
    else if (t < 8192 + NSMALL) smalls[t - 8192] = 0.f;
    else Pbpad[t - (8192 + NSMALL)] = 0;
  }
}

__global__ void init_rs_kernel(const float* __restrict__ y, float* __restrict__ rs0,
                               float* __restrict__ pn0, float* __restrict__ sc0) {
  int t = threadIdx.x;
  float s = 0.f;
  for (int i = t; i < NN; i += 256) { float v = y[i]; s += v * v; }
  float tot = block_sum(s);
  if (t == 0) { rs0[0] = tot; pn0[0] = tot; }
  if (t >= 1 && t <= 100) { rs0[t] = (float)NN; pn0[t] = (float)NN; }
  if (t < 128) sc0[t] = 1.f;
}

// ---------------- SLQ: Sturm bisection + Gauss-weight recurrence, fp64 ----------------
__global__ __launch_bounds__(64, 1) void slq_kernel(
    const float* __restrict__ AL, const float* __restrict__ BE,
    float* __restrict__ QP) {
  __shared__ double sd[PITER], se[PITER];
  int lane = threadIdx.x;
  int c = blockIdx.x + 1;
  if (lane < PITER) {
    double a = (double)AL[lane * 128 + c];
    double dd = 1.0 / a;
    if (lane > 0) {
      double ap = (double)AL[(lane - 1) * 128 + c];
      double bp = (double)BE[(lane - 1) * 128 + c];
      dd += bp / ap;
    }
    sd[lane] = dd;
    double ee = 0.0;
    if (lane < PITER - 1) {
      double b = (double)BE[lane * 128 + c];
      ee = sqrt(b) / a;
    }
    se[lane] = ee;
  }
  __syncthreads();
  double d[PITER], e[PITER];
  #pragma unroll
  for (int i = 0; i < PITER; ++i) { d[i] = sd[i]; e[i] = se[i]; }

  float quadk = 0.f;
  if (lane < PITER) {
    double lo = 1e300, hi = -1e300;
    #pragma unroll
    for (int i = 0; i < PITER; ++i) {
      double r = e[i] + (i > 0 ? e[i - 1] : 0.0);
      lo = fmin(lo, d[i] - r);
      hi = fmax(hi, d[i] + r);
    }
    int k = lane;
    for (int it = 0; it < 48; ++it) {
      double mid = 0.5 * (lo + hi);
      int cnt = 0;
      double q = d[0] - mid;
      cnt += (q < 0.0);
      #pragma unroll
      for (int i = 1; i < PITER; ++i) {
        double aq = fabs(q);
        if (aq < 1e-30) q = (q < 0.0) ? -1e-30 : 1e-30;
        q = d[i] - mid - (e[i - 1] * e[i - 1]) / q;
        cnt += (q < 0.0);
      }
      if (cnt > k) hi = mid; else lo = mid;
    }
    double lam = 0.5 * (lo + hi);
    double e0 = fmax(e[0], 1e-150);
    double vprev = 1.0;
    double vcur = (lam - d[0]) / e0;
    double s = 1.0 + vcur * vcur;
    double scale2 = 1.0;
    #pragma unroll
    for (int i = 1; i < PITER - 1; ++i) {
      double ei = fmax(e[i], 1e-150);
      double vnext = ((lam - d[i]) * vcur - e[i - 1] * vprev) / ei;
      if (fabs(vnext) > 1e150) {
        vnext *= 1e-150; vcur *= 1e-150; s *= 1e-300; scale2 *= 1e-300;
      }
      vprev = vcur; vcur = vnext;
      s += vcur * vcur;
    }
    double w = scale2 / s;
    double lc = lam > 1e-12 ? lam : 1e-12;
    quadk = (float)(w * log(lc));
  }
  #pragma unroll
  for (int o = 32; o > 0; o >>= 1) quadk += __shfl_down(quadk, o);
  if (lane == 0) QP[blockIdx.x] = quadk;
}

// ---------------- final: ydot + combine ----------------
__global__ void final2_kernel(const float* __restrict__ y, const float* __restrict__ X0,
                              const float* __restrict__ QP, float* __restrict__ out) {
  int t = threadIdx.x;
  float s = 0.f;
  for (int i = t; i < NN; i += 256) s += y[i] * X0[i];
  float ydot = block_sum(s);
  __syncthreads();
  float q = (t < 100) ? QP[t] : 0.f;
  float qsum = block_sum(q);
  if (t == 0) {
    float logdet = (float)NN * (qsum * 0.01f);
    out[0] = -0.5f * ydot - 0.5f * logdet - (float)NN * 0.5f * 1.8378770664093454f;
  }
}

extern "C" void kernel_launch(void* const* d_in, const int* in_sizes, int n_in,
                              void* d_out, int out_size, void* d_ws, size_t ws_size,
                              hipStream_t stream) {
  const float* K = (const float*)d_in[0];
  const float* y = (const float*)d_in[1];
  const float* Z = (const float*)d_in[2];
  float* out = (float*)d_out;
  char* ws = (char*)d_ws;
  if (ws_size < 89796096ull) return;  // need ~85.6 MiB

  unsigned char* Kbt = (unsigned char*)(ws + 0ull);       // 67,108,864 (tiled panels)
  unsigned char* Pb = (unsigned char*)(ws + 67108864ull); //  1,048,576 (128 cols)
  float* P   = (float*)(ws + 68157440ull);                //  3,309,568 (101 cols)
  float* R   = (float*)(ws + 71467008ull);                //  3,309,568
  __half* Vp = (__half*)(ws + 74776576ull);               // 14,680,064 (8 splits x 112 cols, fp16)
  float* X0  = (float*)(ws + 89456640ull);                //     32,768
  float* PVP = (float*)(ws + 89489408ull);                //    212,992 (512 x 104)
  float* SM  = (float*)(ws + 89702400ull);                //     93,696 scalar block
  float* RS = SM;               // [31][128]
  float* AL = SM + 7808;        // [30][128]
  float* BE = SM + 11648;       // [30][128]
  float* PN = SM + 15488;       // [31][128]
  float* SC = SM + 19456;       // [31][128]
  float* QP = (float*)(ws + 74776576ull);  // 100 floats, reuses Vp after CG loop

  cast_k_kernel<<<8192, 256, 0, stream>>>(K, Kbt);
  init_vec_kernel<<<dim3(32, 101), 256, 0, stream>>>(y, Z, P, R, Pb);
  init_misc_kernel<<<240, 256, 0, stream>>>(X0, SM, Pb + (size_t)NCOLS * NN);
  init_rs_kernel<<<1, 256, 0, stream>>>(y, RS, PN, SC);

  for (int it = 0; it < PITER; ++it) {
    gemm_kernel<<<512, 256, 0, stream>>>(Kbt, Pb, P, SC + it * 128, Vp, PVP);
    update1_kernel<<<dim3(8, 101), 256, 0, stream>>>(Vp, P, R, X0, PVP,
        RS + it * 128, RS + (it + 1) * 128, AL + it * 128);
    update2_kernel<<<dim3(8, 101), 256, 0, stream>>>(R, P, Pb, RS + it * 128,
        RS + (it + 1) * 128, PN + it * 128, PN + (it + 1) * 128,
        SC + (it + 1) * 128, BE + it * 128);
  }
  slq_kernel<<<100, 64, 0, stream>>>(AL, BE, QP);
  final2_kernel<<<1, 256, 0, stream>>>(y, X0, QP, out);
}

// Round 5
// 1915.548 us; speedup vs baseline: 3.6752x; 1.0608x over previous
//
#include <hip/hip_runtime.h>
#include <hip/hip_fp16.h>

#define NN 8192
#define NCOLS 101      // y + 100 probes
#define CPW 112        // Vp stored columns (101 used, 112 allocated)
#define BN 128         // compute columns (padded; Pb cols 101..127 are zero)
#define BM 128
#define KSPL 8
#define KCH (NN / KSPL)    // 1024 fp8 elems (=bytes) per split
#define NSTEP (KCH / 128)  // 8 steps of BK=128
#define PITER 30
#define PVLD 104           // pvp row stride (101 rounded up)

typedef __attribute__((ext_vector_type(4))) float f32x4;

__device__ __forceinline__ void async_copy16(const void* g, void* l) {
  __builtin_amdgcn_global_load_lds(
      (const __attribute__((address_space(1))) unsigned int*)g,
      (__attribute__((address_space(3))) unsigned int*)l, 16, 0, 0);
}

__device__ __forceinline__ unsigned int pack_fp8x4(float x, float y, float z, float w) {
  unsigned int v = __builtin_amdgcn_cvt_pk_fp8_f32(x, y, 0, false);
  v = __builtin_amdgcn_cvt_pk_fp8_f32(z, w, v, true);
  return v;
}

// 256-thread (4-wave) block sum; valid on thread 0 only; leading barrier makes
// back-to-back calls safe.
__device__ __forceinline__ float block_sum(float v) {
  __shared__ float sw[4];
  __syncthreads();
  #pragma unroll
  for (int o = 32; o > 0; o >>= 1) v += __shfl_down(v, o);
  int w = threadIdx.x >> 6;
  if ((threadIdx.x & 63) == 0) sw[w] = v;
  __syncthreads();
  float r = 0.f;
  if (threadIdx.x < 4) r = sw[threadIdx.x];
  r += __shfl_down(r, 2);
  r += __shfl_down(r, 1);
  return r;
}

// 1024-thread (16-wave) block sum; valid on thread 0 only.
__device__ __forceinline__ float block_sum1024(float v) {
  __shared__ float sw[16];
  __syncthreads();
  #pragma unroll
  for (int o = 32; o > 0; o >>= 1) v += __shfl_down(v, o);
  int w = threadIdx.x >> 6;
  if ((threadIdx.x & 63) == 0) sw[w] = v;
  __syncthreads();
  float r = 0.f;
  if (threadIdx.x < 16) r = sw[threadIdx.x];
  r += __shfl_down(r, 8);
  r += __shfl_down(r, 4);
  r += __shfl_down(r, 2);
  r += __shfl_down(r, 1);
  return r;
}

// ---------------- GEMM: Vp[kz] = K-panel @ Phat (fp8 MFMA) + pv partials ----------------
// Byte-identical to R4 (models to ~12us, HBM-bound on its 64MB Kb stream). Kbt is tiled:
// panel bx is 128KB contiguous [step][row][128B]; XOR swizzle applied via source offset.
// 128x128 block tile, 4 waves (64x64 wave tile), 2-phase dbuf, one barrier per step.
__global__ __launch_bounds__(256, 2) void gemm_kernel(
    const unsigned char* __restrict__ Kbt,
    const unsigned char* __restrict__ Pb,
    const float* __restrict__ Pf,
    const float* __restrict__ SCit,
    __half* __restrict__ Vp,
    float* __restrict__ pvp) {
  __shared__ __align__(16) unsigned char smem[65536];
  unsigned char* sA = smem;          // [2][BM*128]
  unsigned char* sB = smem + 32768;  // [2][BN*128]
  float* sC = (float*)smem;          // [BM][113], post-loop overlay

  int bx = blockIdx.x;
  int kz = bx & 7;
  int rb = bx >> 3;
  int tid = threadIdx.x;
  int lane = tid & 63;
  int w = tid >> 6;
  int r0 = rb * BM;
  int k0 = kz * KCH;
  int lrow = lane >> 3;
  int gseg = (lane & 7) ^ lrow;
  int asrc = lrow * 128 + gseg * 16;
  int mm = lane & 15;
  int quad = lane >> 4;
  int q1 = quad >> 1, q0 = quad & 1;
  int wm = w >> 1, wn = w & 1;   // wave grid 2M x 2N, wave tile 64x64

  const unsigned char* Apanel = Kbt + ((size_t)bx << 17);

  int aBase[4], aXor[4], bBase[4], bXor[4];
  #pragma unroll
  for (int i = 0; i < 4; ++i) {
    int arow = wm * 64 + i * 16 + mm;
    aBase[i] = arow * 128 + (q0 << 3);
    aXor[i] = (arow & 7) << 4;
    int bcol = wn * 64 + i * 16 + mm;
    bBase[i] = bcol * 128 + (q0 << 3);
    bXor[i] = (bcol & 7) << 4;
  }

  f32x4 acc[4][4];
  #pragma unroll
  for (int i = 0; i < 4; ++i)
    #pragma unroll
    for (int j = 0; j < 4; ++j) acc[i][j] = (f32x4){0.f, 0.f, 0.f, 0.f};

  auto stage = [&](int s, int buf) {
    int kk = k0 + s * 128;
    #pragma unroll
    for (int q = 0; q < 4; ++q) {  // wave w stages rows/cols w*32 + q*8 + lrow
      async_copy16(Apanel + (s << 14) + (w * 32 + q * 8) * 128 + asrc,
                   sA + buf * 16384 + (w * 32 + q * 8) * 128);
      async_copy16(Pb + (size_t)(w * 32 + q * 8 + lrow) * NN + kk + gseg * 16,
                   sB + buf * 16384 + (w * 32 + q * 8) * 128);
    }
  };

  stage(0, 0);
  __syncthreads();  // vmcnt(0): prologue tile landed

  #pragma unroll 2
  for (int s = 0; s < NSTEP; ++s) {
    int cur = s & 1;
    if (s + 1 < NSTEP) stage(s + 1, cur ^ 1);  // prefetch next tile
    const unsigned char* A = sA + cur * 16384;
    const unsigned char* B = sB + cur * 16384;
    #pragma unroll
    for (int kh = 0; kh < 4; ++kh) {
      int s16 = (kh * 2 + q1) << 4;
      long long aF[4], bF[4];
      #pragma unroll
      for (int i = 0; i < 4; ++i) {
        aF[i] = *(const long long*)(A + aBase[i] + (s16 ^ aXor[i]));
        bF[i] = *(const long long*)(B + bBase[i] + (s16 ^ bXor[i]));
      }
      #pragma unroll
      for (int i = 0; i < 4; ++i)
        #pragma unroll
        for (int j = 0; j < 4; ++j)
          acc[i][j] = __builtin_amdgcn_mfma_f32_16x16x32_fp8_fp8(aF[i], bF[j], acc[i][j], 0, 0, 0);
    }
    __syncthreads();  // lgkmcnt(0) WAR + vmcnt(0) RAW for the dbuf swap
  }
  // epilogue: transpose through LDS (C/D frag layout: col=lane&15, row=quad*4+r)
  #pragma unroll
  for (int i = 0; i < 4; ++i)
    #pragma unroll
    for (int j = 0; j < 4; ++j) {
      int ctile = wn * 64 + j * 16;
      if (ctile >= CPW) continue;
      #pragma unroll
      for (int r = 0; r < 4; ++r)
        sC[(wm * 64 + i * 16 + quad * 4 + r) * 113 + ctile + mm] = acc[i][j][r];
    }
  __syncthreads();
  const size_t SPL = (size_t)CPW * NN;
  __half* Vout = Vp + (size_t)kz * SPL;
  for (int idx = tid; idx < BM * CPW; idx += 256) {
    int col = idx >> 7;
    int row = idx & 127;
    if (col < NCOLS)
      Vout[(size_t)col * NN + r0 + row] = __float2half(sC[row * 113 + col] * SCit[col]);
  }
  // pv partial: wave g handles cols {g, g+4, ...}; lanes = rows (coalesced P reads)
  int rr = tid & 63;
  int g = tid >> 6;
  for (int j = 0; j < 26; ++j) {
    int c = g + j * 4;
    float prod = 0.f;
    if (c < NCOLS)
      prod = (sC[rr * 113 + c] * Pf[(size_t)c * NN + r0 + rr] +
              sC[(rr + 64) * 113 + c] * Pf[(size_t)c * NN + r0 + 64 + rr]) * SCit[c];
    #pragma unroll
    for (int o = 32; o > 0; o >>= 1) prod += __shfl_down(prod, o);
    if (rr == 0 && c < NCOLS) pvp[(size_t)bx * PVLD + c] = prod;
  }
}

// ---------------- fused update: ONE block per column, whole chain block-local ----------
// alpha = rs/pv; R -= a*V(sum of 8 fp16 splits); X0 += a*P (c==0); rsn = |R|^2 via
// block_sum (NO cross-block atomic); beta; P = R + b*P; Pb = fp8(P/sc); bookkeeping.
// Replaces update1+update2: one dispatch instead of two, no rs_new global round-trip,
// no R re-read, pv reduced once per column instead of 8x.
__global__ __launch_bounds__(1024, 1) void update_kernel(
    const __half* __restrict__ Vp, float* __restrict__ P,
    float* __restrict__ R, float* __restrict__ X0,
    unsigned char* __restrict__ Pb, const float* __restrict__ pvp,
    float* __restrict__ SM, int it) {
  float* RS = SM;                // [31][128]
  float* AL = SM + 7808;         // [30][128]
  float* BE = SM + 11648;        // [30][128]
  float* PN = SM + 15488;        // [31][128]
  float* SC = SM + 19456;        // [31][128]
  __shared__ float sbc[2];

  int c = blockIdx.x;   // 0..100
  int t = threadIdx.x;  // 0..1023
  const size_t SPL = (size_t)CPW * NN;
  size_t base = (size_t)c * NN;

  // pv total for this column (512 gemm-block partials)
  float pvv = (t < 512) ? pvp[(size_t)t * PVLD + c] : 0.f;
  float pvtot = block_sum1024(pvv);
  float rs_old = RS[it * 128 + c];
  if (t == 0) sbc[0] = rs_old / pvtot;
  __syncthreads();
  float alpha = sbc[0];

  // R update (keep r in regs for the P phase); rn partial
  float4 rv[2];
  float rn = 0.f;
  #pragma unroll
  for (int j = 0; j < 2; ++j) {
    size_t off = base + j * 4096 + t * 4;
    float4 v = {0.f, 0.f, 0.f, 0.f};
    #pragma unroll
    for (int sp = 0; sp < KSPL; ++sp) {
      const __half2* ph = (const __half2*)(Vp + sp * SPL + off);
      float2 f01 = __half22float2(ph[0]);
      float2 f23 = __half22float2(ph[1]);
      v.x += f01.x; v.y += f01.y; v.z += f23.x; v.w += f23.y;
    }
    float4 r = *(float4*)(R + off);
    r.x -= alpha * v.x; r.y -= alpha * v.y;
    r.z -= alpha * v.z; r.w -= alpha * v.w;
    *(float4*)(R + off) = r;
    rv[j] = r;
    rn += r.x * r.x + r.y * r.y + r.z * r.z + r.w * r.w;
    if (c == 0) {
      size_t xo = j * 4096 + t * 4;
      float4 x = *(float4*)(X0 + xo);
      float4 p = *(const float4*)(P + off);
      x.x += alpha * p.x; x.y += alpha * p.y;
      x.z += alpha * p.z; x.w += alpha * p.w;
      *(float4*)(X0 + xo) = x;
    }
  }
  float rsn = block_sum1024(rn);
  if (t == 0) {
    float beta = rsn / rs_old;
    float pnn = rsn + beta * beta * PN[it * 128 + c];  // ||P_new||^2 (CG identity)
    float sc = exp2f(roundf(0.5f * log2f(pnn * (1.f / 8192.f))));
    AL[it * 128 + c] = alpha;
    BE[it * 128 + c] = beta;
    PN[(it + 1) * 128 + c] = pnn;
    SC[(it + 1) * 128 + c] = sc;
    RS[(it + 1) * 128 + c] = rsn;
    sbc[0] = beta;
    sbc[1] = 1.f / sc;
  }
  __syncthreads();
  if (it < PITER - 1) {
    float beta = sbc[0], inv = sbc[1];
    #pragma unroll
    for (int j = 0; j < 2; ++j) {
      size_t off = base + j * 4096 + t * 4;
      float4 p = *(float4*)(P + off);
      p.x = rv[j].x + beta * p.x; p.y = rv[j].y + beta * p.y;
      p.z = rv[j].z + beta * p.z; p.w = rv[j].w + beta * p.w;
      *(float4*)(P + off) = p;
      *(unsigned int*)(Pb + off) = pack_fp8x4(p.x * inv, p.y * inv, p.z * inv, p.w * inv);
    }
  }
}

// ---------------- fused init: cast K->Kbt panels + vec init + zero + rs0 --------------
// Kbt layout: panel p = rb*8+kz (== gemm blockIdx): [step s][row 0..127][128 B].
// Element (r,c) of K -> p = (r>>7)*8 + (c>>10); s = (c>>7)&7; row = r&127; byte = c&127.
__global__ void init_all(const float* __restrict__ K, const float* __restrict__ y,
                         const float* __restrict__ Z, unsigned char* __restrict__ Kbt,
                         unsigned char* __restrict__ Pb, float* __restrict__ P,
                         float* __restrict__ R, float* __restrict__ X0,
                         float* __restrict__ SM) {
  int b = blockIdx.x;
  int t = threadIdx.x;
  int gid = b * 256 + t;
  const int gsz = 512 * 256;
  // cast K -> tiled fp8 panels
  for (size_t u = gid; u < (size_t)NN * NN / 16; u += gsz) {
    size_t d = u * 16;
    int p = (int)(d >> 17);
    int rem = (int)(d & 131071);
    int s = rem >> 14;
    int row = (rem >> 7) & 127;
    int cb = rem & 127;
    int r = (p >> 3) * 128 + row;
    int c = (p & 7) * KCH + s * 128 + cb;
    const float* src = K + (size_t)r * NN + c;
    float4 f0 = *(const float4*)(src);
    float4 f1 = *(const float4*)(src + 4);
    float4 f2 = *(const float4*)(src + 8);
    float4 f3 = *(const float4*)(src + 12);
    uint4 o;
    o.x = pack_fp8x4(f0.x, f0.y, f0.z, f0.w);
    o.y = pack_fp8x4(f1.x, f1.y, f1.z, f1.w);
    o.z = pack_fp8x4(f2.x, f2.y, f2.z, f2.w);
    o.w = pack_fp8x4(f3.x, f3.y, f3.z, f3.w);
    *(uint4*)(Kbt + d) = o;
  }
  // P/R/Pb from y,Z
  for (int v = gid; v < NCOLS * NN; v += gsz) {
    int c = v >> 13;
    int i = v & 8191;
    float val = (c == 0) ? y[i] : Z[(size_t)i * 100 + (c - 1)];
    size_t off = (size_t)c * NN + i;
    P[off] = val;
    R[off] = val;
    Pb[off] = (unsigned char)(__builtin_amdgcn_cvt_pk_fp8_f32(val, 0.f, 0, false) & 0xFF);
  }
  // zero X0 and Pb padding cols 101..127
  for (int i = gid; i < 8192 + 27 * NN; i += gsz) {
    if (i < 8192) X0[i] = 0.f;
    else Pb[(size_t)NCOLS * NN + (i - 8192)] = 0;
  }
  // scalar seeds (block 511): RS/PN row 0, SC row 0
  if (b == 511) {
    float* RS = SM;
    float* PN = SM + 15488;
    float* SC = SM + 19456;
    float s = 0.f;
    for (int i = t; i < NN; i += 256) { float v = y[i]; s += v * v; }
    float tot = block_sum(s);
    if (t == 0) { RS[0] = tot; PN[0] = tot; }
    if (t >= 1 && t <= 100) { RS[t] = (float)NN; PN[t] = (float)NN; }
    if (t < 128) SC[t] = 1.f;
  }
}

// ---------------- SLQ: Sturm bisection + Gauss-weight recurrence, fp64 ----------------
__global__ __launch_bounds__(64, 1) void slq_kernel(
    const float* __restrict__ AL, const float* __restrict__ BE,
    float* __restrict__ QP) {
  __shared__ double sd[PITER], se[PITER];
  int lane = threadIdx.x;
  int c = blockIdx.x + 1;
  if (lane < PITER) {
    double a = (double)AL[lane * 128 + c];
    double dd = 1.0 / a;
    if (lane > 0) {
      double ap = (double)AL[(lane - 1) * 128 + c];
      double bp = (double)BE[(lane - 1) * 128 + c];
      dd += bp / ap;
    }
    sd[lane] = dd;
    double ee = 0.0;
    if (lane < PITER - 1) {
      double b = (double)BE[lane * 128 + c];
      ee = sqrt(b) / a;
    }
    se[lane] = ee;
  }
  __syncthreads();
  double d[PITER], e[PITER];
  #pragma unroll
  for (int i = 0; i < PITER; ++i) { d[i] = sd[i]; e[i] = se[i]; }

  float quadk = 0.f;
  if (lane < PITER) {
    double lo = 1e300, hi = -1e300;
    #pragma unroll
    for (int i = 0; i < PITER; ++i) {
      double r = e[i] + (i > 0 ? e[i - 1] : 0.0);
      lo = fmin(lo, d[i] - r);
      hi = fmax(hi, d[i] + r);
    }
    int k = lane;
    for (int it = 0; it < 48; ++it) {
      double mid = 0.5 * (lo + hi);
      int cnt = 0;
      double q = d[0] - mid;
      cnt += (q < 0.0);
      #pragma unroll
      for (int i = 1; i < PITER; ++i) {
        double aq = fabs(q);
        if (aq < 1e-30) q = (q < 0.0) ? -1e-30 : 1e-30;
        q = d[i] - mid - (e[i - 1] * e[i - 1]) / q;
        cnt += (q < 0.0);
      }
      if (cnt > k) hi = mid; else lo = mid;
    }
    double lam = 0.5 * (lo + hi);
    double e0 = fmax(e[0], 1e-150);
    double vprev = 1.0;
    double vcur = (lam - d[0]) / e0;
    double s = 1.0 + vcur * vcur;
    double scale2 = 1.0;
    #pragma unroll
    for (int i = 1; i < PITER - 1; ++i) {
      double ei = fmax(e[i], 1e-150);
      double vnext = ((lam - d[i]) * vcur - e[i - 1] * vprev) / ei;
      if (fabs(vnext) > 1e150) {
        vnext *= 1e-150; vcur *= 1e-150; s *= 1e-300; scale2 *= 1e-300;
      }
      vprev = vcur; vcur = vnext;
      s += vcur * vcur;
    }
    double w = scale2 / s;
    double lc = lam > 1e-12 ? lam : 1e-12;
    quadk = (float)(w * log(lc));
  }
  #pragma unroll
  for (int o = 32; o > 0; o >>= 1) quadk += __shfl_down(quadk, o);
  if (lane == 0) QP[blockIdx.x] = quadk;
}

// ---------------- final: ydot + combine ----------------
__global__ void final2_kernel(const float* __restrict__ y, const float* __restrict__ X0,
                              const float* __restrict__ QP, float* __restrict__ out) {
  int t = threadIdx.x;
  float s = 0.f;
  for (int i = t; i < NN; i += 256) s += y[i] * X0[i];
  float ydot = block_sum(s);
  __syncthreads();
  float q = (t < 100) ? QP[t] : 0.f;
  float qsum = block_sum(q);
  if (t == 0) {
    float logdet = (float)NN * (qsum * 0.01f);
    out[0] = -0.5f * ydot - 0.5f * logdet - (float)NN * 0.5f * 1.8378770664093454f;
  }
}

extern "C" void kernel_launch(void* const* d_in, const int* in_sizes, int n_in,
                              void* d_out, int out_size, void* d_ws, size_t ws_size,
                              hipStream_t stream) {
  const float* K = (const float*)d_in[0];
  const float* y = (const float*)d_in[1];
  const float* Z = (const float*)d_in[2];
  float* out = (float*)d_out;
  char* ws = (char*)d_ws;
  if (ws_size < 89796096ull) return;  // need ~85.6 MiB

  unsigned char* Kbt = (unsigned char*)(ws + 0ull);       // 67,108,864 (tiled panels)
  unsigned char* Pb = (unsigned char*)(ws + 67108864ull); //  1,048,576 (128 cols)
  float* P   = (float*)(ws + 68157440ull);                //  3,309,568 (101 cols)
  float* R   = (float*)(ws + 71467008ull);                //  3,309,568
  __half* Vp = (__half*)(ws + 74776576ull);               // 14,680,064 (8 splits x 112 cols, fp16)
  float* X0  = (float*)(ws + 89456640ull);                //     32,768
  float* PVP = (float*)(ws + 89489408ull);                //    212,992 (512 x 104)
  float* SM  = (float*)(ws + 89702400ull);                //     93,696 scalar block
  float* AL = SM + 7808;        // [30][128]
  float* BE = SM + 11648;       // [30][128]
  float* SC = SM + 19456;       // [31][128]
  float* QP = (float*)(ws + 74776576ull);  // 100 floats, reuses Vp after CG loop

  init_all<<<512, 256, 0, stream>>>(K, y, Z, Kbt, Pb, P, R, X0, SM);

  for (int it = 0; it < PITER; ++it) {
    gemm_kernel<<<512, 256, 0, stream>>>(Kbt, Pb, P, SC + it * 128, Vp, PVP);
    update_kernel<<<NCOLS, 1024, 0, stream>>>(Vp, P, R, X0, Pb, PVP, SM, it);
  }
  slq_kernel<<<100, 64, 0, stream>>>(AL, BE, QP);
  final2_kernel<<<1, 256, 0, stream>>>(y, X0, QP, out);
}